// Round 2
// baseline (34952.277 us; speedup 1.0000x reference)
//
#include <hip/hip_runtime.h>

#define Hh 512
#define Bb 256
#define Tt 512
#define NPR 128
#define BH (Bb*Hh)
#define BKC 64

struct CellP {
  const float* A1; const float* W1;   // GEMM1: g += A1[b,:] . W1[n,:], K=512
  const float* A2; const float* W2;   // optional GEMM2 (same shape), nullptr if none
  const float* bias;                  // (4H)
  const float* svec; int sstride;     // scalar input mode: s[b] = svec[b*sstride]
  const float* sW;                    // (4H) column: g += s[b]*sW[n]
  const float* predH;                 // pred mode: s[b] = dot(predH[b,:],linW)+linb
  const float* linW; const float* linb;
  float* predOut; int predStride;     // also write s[b] to predOut[b*predStride]
  const float* cin; float* cout;      // (B,H) cell state (in-place ok)
  float* hout;                        // (B,H)
  int active;
};

__global__ __launch_bounds__(256) void lstm_stage(CellP pa, CellP pb) {
  __shared__ float As[BKC][64];   // k-major: As[k][local_b]
  __shared__ float Ws[64][68];    // row = g*16 + jthr, padded stride 68
  __shared__ float sS[64];

  CellP p = (blockIdx.x & 128) ? pb : pa;
  if (!p.active) return;

  const int blk   = blockIdx.x & 127;
  const int btile = blk & 3;          // 4 tiles of 64 batch rows
  const int jtile = blk >> 2;         // 32 tiles of 16 hidden cols
  const int tid   = threadIdx.x;
  const int bthr  = tid >> 4;         // 0..15 (4 b each)
  const int jthr  = tid & 15;         // 0..15 (1 j each)
  const int j     = jtile*16 + jthr;
  const int b0loc = bthr*4;

  // ---- per-batch scalar input (x value, or prediction dot-product) ----
  if (p.svec != nullptr || p.predH != nullptr) {
    const int bl = tid >> 2, part = tid & 3;
    const int bg = btile*64 + bl;
    if (p.svec != nullptr) {
      if (part == 0) sS[bl] = p.svec[(long long)bg * p.sstride];
    } else {
      const float* ph = p.predH + (long long)bg * Hh;
      float a = 0.f;
      for (int k = part; k < Hh; k += 4) a = fmaf(ph[k], p.linW[k], a);
      a += __shfl_xor(a, 1, 64);
      a += __shfl_xor(a, 2, 64);
      if (part == 0) {
        const float s = a + p.linb[0];
        sS[bl] = s;
        if (jtile == 0 && p.predOut != nullptr)
          p.predOut[(long long)bg * p.predStride] = s;
      }
    }
  }

  float acc[4][4];   // [gate][r]
  #pragma unroll
  for (int g = 0; g < 4; ++g)
    #pragma unroll
    for (int r = 0; r < 4; ++r) acc[g][r] = 0.f;

  const int ngemm = (p.A2 != nullptr) ? 2 : 1;
  for (int gm = 0; gm < ngemm; ++gm) {
    const float* Ag = gm ? p.A2 : p.A1;
    const float* Wg = gm ? p.W2 : p.W1;
    for (int k0 = 0; k0 < Hh; k0 += BKC) {
      __syncthreads();
      { // stage A tile (64 b x 64 k), transpose to k-major
        const int row = tid >> 2;
        const int kq  = (tid & 3) << 4;
        const float* src = Ag + (long long)(btile*64 + row)*Hh + k0 + kq;
        #pragma unroll
        for (int u = 0; u < 16; u += 4) {
          const float4 v = *(const float4*)(src + u);
          As[kq+u+0][row] = v.x;
          As[kq+u+1][row] = v.y;
          As[kq+u+2][row] = v.z;
          As[kq+u+3][row] = v.w;
        }
      }
      { // stage W tile: rows n = g*H + jtile*16 + jj  ->  Ws[g*16+jj][k]
        const int r  = tid >> 2;          // g = r>>4, jj = r&15
        const int kq = (tid & 3) << 4;
        const int n  = (r >> 4)*Hh + jtile*16 + (r & 15);
        const float* src = Wg + (long long)n*Hh + k0 + kq;
        #pragma unroll
        for (int u = 0; u < 16; u += 4)
          *(float4*)&Ws[r][kq+u] = *(const float4*)(src + u);
      }
      __syncthreads();
      #pragma unroll 2
      for (int kk = 0; kk < BKC; kk += 4) {
        float4 av[4], wv[4];
        #pragma unroll
        for (int u = 0; u < 4; ++u) av[u] = *(const float4*)&As[kk+u][b0loc];
        #pragma unroll
        for (int g = 0; g < 4; ++g) wv[g] = *(const float4*)&Ws[g*16 + jthr][kk];
        #pragma unroll
        for (int g = 0; g < 4; ++g) {
          const float* wp = (const float*)&wv[g];
          #pragma unroll
          for (int u = 0; u < 4; ++u) {
            const float* ap = (const float*)&av[u];
            const float wgu = wp[u];
            acc[g][0] = fmaf(ap[0], wgu, acc[g][0]);
            acc[g][1] = fmaf(ap[1], wgu, acc[g][1]);
            acc[g][2] = fmaf(ap[2], wgu, acc[g][2]);
            acc[g][3] = fmaf(ap[3], wgu, acc[g][3]);
          }
        }
      }
    }
  }

  // ---- epilogue: gates -> c,h ----
  const bool hasS = (p.svec != nullptr) || (p.predH != nullptr);
  float swv[4] = {0.f,0.f,0.f,0.f};
  if (p.sW != nullptr) {
    swv[0] = p.sW[j];       swv[1] = p.sW[Hh+j];
    swv[2] = p.sW[2*Hh+j];  swv[3] = p.sW[3*Hh+j];
  }
  const float bi = p.bias[j],      bf = p.bias[Hh+j];
  const float bgg = p.bias[2*Hh+j], bo = p.bias[3*Hh+j];
  #pragma unroll
  for (int r = 0; r < 4; ++r) {
    const int bl = b0loc + r;
    const long long b = btile*64 + bl;
    const float sv = hasS ? sS[bl] : 0.f;
    const float gi = acc[0][r] + bi  + sv*swv[0];
    const float gf = acc[1][r] + bf  + sv*swv[1];
    const float gg = acc[2][r] + bgg + sv*swv[2];
    const float go = acc[3][r] + bo  + sv*swv[3];
    const long long idx = b*Hh + j;
    const float si = 1.f/(1.f + expf(-gi));
    const float sf = 1.f/(1.f + expf(-gf));
    const float so = 1.f/(1.f + expf(-go));
    const float c2 = sf * p.cin[idx] + si * tanhf(gg);
    const float h2 = so * tanhf(c2);
    p.cout[idx] = c2;
    p.hout[idx] = h2;
  }
}

__global__ __launch_bounds__(256) void final_pred(const float* __restrict__ h1,
                                                  const float* __restrict__ linW,
                                                  const float* __restrict__ linb,
                                                  float* __restrict__ out) {
  const int b    = blockIdx.x*8 + (threadIdx.x >> 5);
  const int lane = threadIdx.x & 31;
  const float* ph = h1 + (long long)b*Hh;
  float a = 0.f;
  for (int k = lane; k < Hh; k += 32) a = fmaf(ph[k], linW[k], a);
  a += __shfl_xor(a, 1, 64);
  a += __shfl_xor(a, 2, 64);
  a += __shfl_xor(a, 4, 64);
  a += __shfl_xor(a, 8, 64);
  a += __shfl_xor(a, 16, 64);
  if (lane == 0) out[(long long)b*NPR + (NPR-1)] = a + linb[0];
}

extern "C" void kernel_launch(void* const* d_in, const int* in_sizes, int n_in,
                              void* d_out, int out_size, void* d_ws, size_t ws_size,
                              hipStream_t stream) {
  const float* x     = (const float*)d_in[0];
  const float* eWih0 = (const float*)d_in[1];
  const float* eWhh0 = (const float*)d_in[2];
  const float* eb0   = (const float*)d_in[3];
  const float* eWih1 = (const float*)d_in[4];
  const float* eWhh1 = (const float*)d_in[5];
  const float* eb1   = (const float*)d_in[6];
  const float* dWih0 = (const float*)d_in[7];
  const float* dWhh0 = (const float*)d_in[8];
  const float* db0   = (const float*)d_in[9];
  const float* dWih1 = (const float*)d_in[10];
  const float* dWhh1 = (const float*)d_in[11];
  const float* db1   = (const float*)d_in[12];
  const float* linW  = (const float*)d_in[13];
  const float* linb  = (const float*)d_in[14];
  float* out = (float*)d_out;

  float* w = (float*)d_ws;
  float* h0[2] = { w,        w + BH };
  float* c0    =   w + 2*BH;
  float* h1[2] = { w + 3*BH, w + 4*BH };
  float* c1    =   w + 5*BH;

  (void)hipMemsetAsync(h0[0], 0, (size_t)BH*4, stream);
  (void)hipMemsetAsync(c0,    0, (size_t)BH*4, stream);
  (void)hipMemsetAsync(h1[0], 0, (size_t)BH*4, stream);
  (void)hipMemsetAsync(c1,    0, (size_t)BH*4, stream);

  CellP off = {};  // all pointers null, active = 0

  // -------- encoder: pipelined stages. stage s: L0(t=s) || L1(t=s-1) --------
  for (int s = 0; s <= Tt; ++s) {
    CellP pa = off, pb = off;
    if (s < Tt) {                       // layer 0, step t=s
      pa.active = 1;
      pa.A1 = h0[s & 1]; pa.W1 = eWhh0;
      pa.bias = eb0;
      pa.svec = x + s; pa.sstride = Tt; pa.sW = eWih0;
      pa.cin = c0; pa.cout = c0; pa.hout = h0[(s+1) & 1];
    }
    if (s >= 1) {                       // layer 1, step u=s-1
      const int u = s - 1;
      pb.active = 1;
      pb.A1 = h1[u & 1]; pb.W1 = eWhh1;
      pb.A2 = h0[s & 1]; pb.W2 = eWih1;   // x-input = h_l0[u]
      pb.bias = eb1;
      pb.cin = c1; pb.cout = c1; pb.hout = h1[(u+1) & 1];
    }
    lstm_stage<<<256, 256, 0, stream>>>(pa, pb);
  }

  // -------- decoder: 128 steps x 2 dependent cells --------
  for (int i = 0; i < NPR; ++i) {
    CellP p0 = off;
    p0.active = 1;
    p0.A1 = h0[i & 1]; p0.W1 = dWhh0;
    p0.bias = db0; p0.sW = dWih0;
    if (i == 0) { p0.svec = x + (Tt-1); p0.sstride = Tt; }
    else {
      p0.predH = h1[i & 1]; p0.linW = linW; p0.linb = linb;
      p0.predOut = out + (i-1); p0.predStride = NPR;
    }
    p0.cin = c0; p0.cout = c0; p0.hout = h0[(i+1) & 1];
    lstm_stage<<<128, 256, 0, stream>>>(p0, off);

    CellP p1 = off;
    p1.active = 1;
    p1.A1 = h1[i & 1]; p1.W1 = dWhh1;
    p1.A2 = h0[(i+1) & 1]; p1.W2 = dWih1;  // x-input = h0_new
    p1.bias = db1;
    p1.cin = c1; p1.cout = c1;
    p1.hout = h1[(i+1) & 1];
    lstm_stage<<<128, 256, 0, stream>>>(p1, off);
  }

  final_pred<<<32, 256, 0, stream>>>(h1[NPR & 1], linW, linb, out);
  (void)in_sizes; (void)n_in; (void)out_size; (void)ws_size;
}

// Round 3
// 23843.262 us; speedup vs baseline: 1.4659x; 1.4659x over previous
//
#include <hip/hip_runtime.h>

#define Hh 512
#define Bb 256
#define Tt 512
#define NPR 128
#define BH (Bb*Hh)            // 131072 elems
#define WN (4*Hh*Hh)          // 1048576 elems per weight matrix

typedef __attribute__((ext_vector_type(8))) short bf8;
typedef __attribute__((ext_vector_type(4))) float f4;

__device__ __forceinline__ unsigned short f2bf(float x) {
  unsigned u = __float_as_uint(x);
  return (unsigned short)((u + 0x7FFFu + ((u >> 16) & 1u)) >> 16);
}
__device__ __forceinline__ float bf2f(unsigned short h) {
  return __uint_as_float((unsigned)h << 16);
}

struct CellP {
  const unsigned short *A1h, *A1l, *W1h, *W1l;   // GEMM1
  const unsigned short *A2h, *A2l, *W2h, *W2l;   // optional GEMM2
  const float* bias;                              // (4H)
  const float* svec; long long sstr;              // scalar input s[b]=svec[b*sstr]
  const float* sW;                                // (4H) column for scalar input
  const unsigned short *pHh, *pHl;                // pred mode: s[b]=dot(h1[b],linW)+linb
  const float *linW, *linb;
  float* predOut; int predStride;
  const float* cin; float* cout;                  // fp32 c state
  unsigned short *hOh, *hOl;                      // bf16 hi/lo h output
  int active;
};

__device__ __forceinline__ void gemm_acc(
    const unsigned short* __restrict__ Ah, const unsigned short* __restrict__ Al,
    const unsigned short* __restrict__ Wh, const unsigned short* __restrict__ Wl,
    size_t aoff, size_t w0, size_t w1, size_t w2, size_t w3,
    f4& acc0, f4& acc1, f4& acc2, f4& acc3)
{
  const unsigned short* pAh = Ah + aoff;
  const unsigned short* pAl = Al + aoff;
  const unsigned short* pW0h = Wh + w0; const unsigned short* pW0l = Wl + w0;
  const unsigned short* pW1h = Wh + w1; const unsigned short* pW1l = Wl + w1;
  const unsigned short* pW2h = Wh + w2; const unsigned short* pW2l = Wl + w2;
  const unsigned short* pW3h = Wh + w3; const unsigned short* pW3l = Wl + w3;
  #pragma unroll 8
  for (int k = 0; k < 16; ++k) {
    const int o = k * 32;                       // 32 bf16 elems per k-step
    const bf8 ah  = *(const bf8*)(pAh + o);
    const bf8 al  = *(const bf8*)(pAl + o);
    const bf8 w0h = *(const bf8*)(pW0h + o);
    const bf8 w1h = *(const bf8*)(pW1h + o);
    const bf8 w2h = *(const bf8*)(pW2h + o);
    const bf8 w3h = *(const bf8*)(pW3h + o);
    const bf8 w0l = *(const bf8*)(pW0l + o);
    const bf8 w1l = *(const bf8*)(pW1l + o);
    const bf8 w2l = *(const bf8*)(pW2l + o);
    const bf8 w3l = *(const bf8*)(pW3l + o);
    // hi*hi
    acc0 = __builtin_amdgcn_mfma_f32_16x16x32_bf16(ah, w0h, acc0, 0, 0, 0);
    acc1 = __builtin_amdgcn_mfma_f32_16x16x32_bf16(ah, w1h, acc1, 0, 0, 0);
    acc2 = __builtin_amdgcn_mfma_f32_16x16x32_bf16(ah, w2h, acc2, 0, 0, 0);
    acc3 = __builtin_amdgcn_mfma_f32_16x16x32_bf16(ah, w3h, acc3, 0, 0, 0);
    // lo*hi
    acc0 = __builtin_amdgcn_mfma_f32_16x16x32_bf16(al, w0h, acc0, 0, 0, 0);
    acc1 = __builtin_amdgcn_mfma_f32_16x16x32_bf16(al, w1h, acc1, 0, 0, 0);
    acc2 = __builtin_amdgcn_mfma_f32_16x16x32_bf16(al, w2h, acc2, 0, 0, 0);
    acc3 = __builtin_amdgcn_mfma_f32_16x16x32_bf16(al, w3h, acc3, 0, 0, 0);
    // hi*lo
    acc0 = __builtin_amdgcn_mfma_f32_16x16x32_bf16(ah, w0l, acc0, 0, 0, 0);
    acc1 = __builtin_amdgcn_mfma_f32_16x16x32_bf16(ah, w1l, acc1, 0, 0, 0);
    acc2 = __builtin_amdgcn_mfma_f32_16x16x32_bf16(ah, w2l, acc2, 0, 0, 0);
    acc3 = __builtin_amdgcn_mfma_f32_16x16x32_bf16(ah, w3l, acc3, 0, 0, 0);
  }
}

__global__ __launch_bounds__(64) void lstm_cell(CellP pa, CellP pb) {
  const int sel = blockIdx.x >> 9;
  const CellP p = sel ? pb : pa;
  if (!p.active) return;

  const int blk  = blockIdx.x & 511;
  const int m0   = (blk & 15) << 4;     // 16 m-tiles of 16 batch rows
  const int j0   = (blk >> 4) << 4;     // 32 j-tiles of 16 hidden cols
  const int lane = threadIdx.x;         // 0..63
  const int row  = lane & 15;           // A: m-row / B: n-col within tile
  const int kg   = lane >> 4;           // k-group 0..3 (8 elems each)

  f4 acc0 = {0.f,0.f,0.f,0.f}, acc1 = acc0, acc2 = acc0, acc3 = acc0;

  const size_t aoff = (size_t)(m0 + row) * Hh + kg * 8;
  const size_t w0   = (size_t)(0*Hh + j0 + row) * Hh + kg * 8;
  const size_t w1   = (size_t)(1*Hh + j0 + row) * Hh + kg * 8;
  const size_t w2   = (size_t)(2*Hh + j0 + row) * Hh + kg * 8;
  const size_t w3   = (size_t)(3*Hh + j0 + row) * Hh + kg * 8;

  gemm_acc(p.A1h, p.A1l, p.W1h, p.W1l, aoff, w0, w1, w2, w3, acc0, acc1, acc2, acc3);
  if (p.A2h != nullptr)
    gemm_acc(p.A2h, p.A2l, p.W2h, p.W2l, aoff, w0, w1, w2, w3, acc0, acc1, acc2, acc3);

  // ---- scalar input s[b] for this thread's 4 batch rows ----
  float sv[4] = {0.f,0.f,0.f,0.f};
  if (p.svec != nullptr) {
    #pragma unroll
    for (int r = 0; r < 4; ++r)
      sv[r] = p.svec[(size_t)(m0 + kg*4 + r) * p.sstr];
  } else if (p.pHh != nullptr) {
    const int bg   = m0 + (lane >> 2);
    const int part = lane & 3;
    const unsigned short* ph = p.pHh + (size_t)bg * Hh + part * 128;
    const unsigned short* pl = p.pHl + (size_t)bg * Hh + part * 128;
    const float* lw = p.linW + part * 128;
    float a = 0.f;
    #pragma unroll 4
    for (int q = 0; q < 128; q += 8) {
      const bf8 vh = *(const bf8*)(ph + q);
      const bf8 vl = *(const bf8*)(pl + q);
      #pragma unroll
      for (int e = 0; e < 8; ++e)
        a = fmaf(bf2f((unsigned short)vh[e]) + bf2f((unsigned short)vl[e]), lw[q + e], a);
    }
    a += __shfl_xor(a, 1, 64);
    a += __shfl_xor(a, 2, 64);
    const float s = a + p.linb[0];
    if (p.predOut != nullptr && j0 == 0 && part == 0)
      p.predOut[(size_t)bg * p.predStride] = s;
    #pragma unroll
    for (int r = 0; r < 4; ++r)
      sv[r] = __shfl(s, ((kg*4 + r) << 2), 64);
  }

  // ---- epilogue: gates -> c,h (fp32), h also re-split to bf16 hi/lo ----
  const int j = j0 + row;
  float swv[4] = {0.f,0.f,0.f,0.f};
  if (p.sW != nullptr) {
    swv[0] = p.sW[j];        swv[1] = p.sW[Hh + j];
    swv[2] = p.sW[2*Hh + j]; swv[3] = p.sW[3*Hh + j];
  }
  const float bi = p.bias[j],        bf = p.bias[Hh + j];
  const float bg = p.bias[2*Hh + j], bo = p.bias[3*Hh + j];
  #pragma unroll
  for (int r = 0; r < 4; ++r) {
    const int b = m0 + kg*4 + r;
    const float gi = acc0[r] + bi + sv[r]*swv[0];
    const float gf = acc1[r] + bf + sv[r]*swv[1];
    const float gg = acc2[r] + bg + sv[r]*swv[2];
    const float go = acc3[r] + bo + sv[r]*swv[3];
    const size_t idx = (size_t)b * Hh + j;
    const float si = 1.f/(1.f + expf(-gi));
    const float sf = 1.f/(1.f + expf(-gf));
    const float so = 1.f/(1.f + expf(-go));
    const float c2 = sf * p.cin[idx] + si * tanhf(gg);
    const float h2 = so * tanhf(c2);
    p.cout[idx] = c2;
    const unsigned short hh = f2bf(h2);
    p.hOh[idx] = hh;
    p.hOl[idx] = f2bf(h2 - bf2f(hh));
  }
}

__global__ __launch_bounds__(256) void conv_w(const float* __restrict__ src,
                                              unsigned short* __restrict__ hi,
                                              unsigned short* __restrict__ lo) {
  const int i = (blockIdx.x * 256 + threadIdx.x) * 4;   // WN = 1M, grid 1024
  const float4 v = *(const float4*)(src + i);
  const unsigned short h0 = f2bf(v.x), h1 = f2bf(v.y), h2 = f2bf(v.z), h3 = f2bf(v.w);
  ushort4 hv; hv.x = h0; hv.y = h1; hv.z = h2; hv.w = h3;
  ushort4 lv;
  lv.x = f2bf(v.x - bf2f(h0)); lv.y = f2bf(v.y - bf2f(h1));
  lv.z = f2bf(v.z - bf2f(h2)); lv.w = f2bf(v.w - bf2f(h3));
  *(ushort4*)(hi + i) = hv;
  *(ushort4*)(lo + i) = lv;
}

__global__ __launch_bounds__(64) void final_pred(const unsigned short* __restrict__ hh,
                                                 const unsigned short* __restrict__ hl,
                                                 const float* __restrict__ linW,
                                                 const float* __restrict__ linb,
                                                 float* __restrict__ out) {
  const int b = blockIdx.x;
  const int lane = threadIdx.x;
  const int k0 = lane * 8;
  const bf8 vh = *(const bf8*)(hh + (size_t)b * Hh + k0);
  const bf8 vl = *(const bf8*)(hl + (size_t)b * Hh + k0);
  float a = 0.f;
  #pragma unroll
  for (int e = 0; e < 8; ++e)
    a = fmaf(bf2f((unsigned short)vh[e]) + bf2f((unsigned short)vl[e]), linW[k0 + e], a);
  #pragma unroll
  for (int off = 1; off < 64; off <<= 1) a += __shfl_xor(a, off, 64);
  if (lane == 0) out[(size_t)b * NPR + (NPR - 1)] = a + linb[0];
}

extern "C" void kernel_launch(void* const* d_in, const int* in_sizes, int n_in,
                              void* d_out, int out_size, void* d_ws, size_t ws_size,
                              hipStream_t stream) {
  const float* x     = (const float*)d_in[0];
  const float* eWih0 = (const float*)d_in[1];
  const float* eWhh0 = (const float*)d_in[2];
  const float* eb0   = (const float*)d_in[3];
  const float* eWih1 = (const float*)d_in[4];
  const float* eWhh1 = (const float*)d_in[5];
  const float* eb1   = (const float*)d_in[6];
  const float* dWih0 = (const float*)d_in[7];
  const float* dWhh0 = (const float*)d_in[8];
  const float* db0   = (const float*)d_in[9];
  const float* dWih1 = (const float*)d_in[10];
  const float* dWhh1 = (const float*)d_in[11];
  const float* db1   = (const float*)d_in[12];
  const float* linW  = (const float*)d_in[13];
  const float* linb  = (const float*)d_in[14];
  float* out = (float*)d_out;

  // ---- workspace layout ----
  unsigned short* wb = (unsigned short*)d_ws;
  unsigned short* eWhh0h = wb + 0*(size_t)WN; unsigned short* eWhh0l = wb + 1*(size_t)WN;
  unsigned short* eWih1h = wb + 2*(size_t)WN; unsigned short* eWih1l = wb + 3*(size_t)WN;
  unsigned short* eWhh1h = wb + 4*(size_t)WN; unsigned short* eWhh1l = wb + 5*(size_t)WN;
  unsigned short* dWhh0h = wb + 6*(size_t)WN; unsigned short* dWhh0l = wb + 7*(size_t)WN;
  unsigned short* dWih1h = wb + 8*(size_t)WN; unsigned short* dWih1l = wb + 9*(size_t)WN;
  unsigned short* dWhh1h = wb + 10*(size_t)WN; unsigned short* dWhh1l = wb + 11*(size_t)WN;
  unsigned short* sb = wb + 12*(size_t)WN;
  unsigned short* h0h[2] = { sb + 0*(size_t)BH, sb + 1*(size_t)BH };
  unsigned short* h0l[2] = { sb + 2*(size_t)BH, sb + 3*(size_t)BH };
  unsigned short* h1h[2] = { sb + 4*(size_t)BH, sb + 5*(size_t)BH };
  unsigned short* h1l[2] = { sb + 6*(size_t)BH, sb + 7*(size_t)BH };
  float* cbase = (float*)(sb + 8*(size_t)BH);
  float* c0 = cbase;
  float* c1 = cbase + BH;

  // ---- init states + convert weights (every call; deterministic) ----
  (void)hipMemsetAsync(h0h[0], 0, (size_t)BH*2, stream);
  (void)hipMemsetAsync(h0l[0], 0, (size_t)BH*2, stream);
  (void)hipMemsetAsync(h1h[0], 0, (size_t)BH*2, stream);
  (void)hipMemsetAsync(h1l[0], 0, (size_t)BH*2, stream);
  (void)hipMemsetAsync(c0, 0, (size_t)BH*4, stream);
  (void)hipMemsetAsync(c1, 0, (size_t)BH*4, stream);

  conv_w<<<1024, 256, 0, stream>>>(eWhh0, eWhh0h, eWhh0l);
  conv_w<<<1024, 256, 0, stream>>>(eWih1, eWih1h, eWih1l);
  conv_w<<<1024, 256, 0, stream>>>(eWhh1, eWhh1h, eWhh1l);
  conv_w<<<1024, 256, 0, stream>>>(dWhh0, dWhh0h, dWhh0l);
  conv_w<<<1024, 256, 0, stream>>>(dWih1, dWih1h, dWih1l);
  conv_w<<<1024, 256, 0, stream>>>(dWhh1, dWhh1h, dWhh1l);

  CellP off = {};   // all null / inactive

  // ---- encoder: stage s runs L0(t=s) and L1(t=s-1) concurrently ----
  for (int s = 0; s <= Tt; ++s) {
    CellP pa = off, pb = off;
    if (s < Tt) {
      pa.active = 1;
      pa.A1h = h0h[s&1]; pa.A1l = h0l[s&1]; pa.W1h = eWhh0h; pa.W1l = eWhh0l;
      pa.bias = eb0;
      pa.svec = x + s; pa.sstr = Tt; pa.sW = eWih0;
      pa.cin = c0; pa.cout = c0;
      pa.hOh = h0h[(s+1)&1]; pa.hOl = h0l[(s+1)&1];
    }
    if (s >= 1) {
      const int u = s - 1;
      pb.active = 1;
      pb.A1h = h1h[u&1]; pb.A1l = h1l[u&1]; pb.W1h = eWhh1h; pb.W1l = eWhh1l;
      pb.A2h = h0h[s&1]; pb.A2l = h0l[s&1]; pb.W2h = eWih1h; pb.W2l = eWih1l;
      pb.bias = eb1;
      pb.cin = c1; pb.cout = c1;
      pb.hOh = h1h[(u+1)&1]; pb.hOl = h1l[(u+1)&1];
    }
    lstm_cell<<<1024, 64, 0, stream>>>(pa, pb);
  }

  // ---- decoder: 128 steps x 2 dependent cells ----
  for (int i = 0; i < NPR; ++i) {
    CellP p0 = off;
    p0.active = 1;
    p0.A1h = h0h[i&1]; p0.A1l = h0l[i&1]; p0.W1h = dWhh0h; p0.W1l = dWhh0l;
    p0.bias = db0; p0.sW = dWih0;
    if (i == 0) { p0.svec = x + (Tt - 1); p0.sstr = Tt; }
    else {
      p0.pHh = h1h[i&1]; p0.pHl = h1l[i&1]; p0.linW = linW; p0.linb = linb;
      p0.predOut = out + (i-1); p0.predStride = NPR;
    }
    p0.cin = c0; p0.cout = c0;
    p0.hOh = h0h[(i+1)&1]; p0.hOl = h0l[(i+1)&1];
    lstm_cell<<<512, 64, 0, stream>>>(p0, off);

    CellP p1 = off;
    p1.active = 1;
    p1.A1h = h1h[i&1]; p1.A1l = h1l[i&1]; p1.W1h = dWhh1h; p1.W1l = dWhh1l;
    p1.A2h = h0h[(i+1)&1]; p1.A2l = h0l[(i+1)&1]; p1.W2h = dWih1h; p1.W2l = dWih1l;
    p1.bias = db1;
    p1.cin = c1; p1.cout = c1;
    p1.hOh = h1h[(i+1)&1]; p1.hOl = h1l[(i+1)&1];
    lstm_cell<<<512, 64, 0, stream>>>(p1, off);
  }

  final_pred<<<Bb, 64, 0, stream>>>(h1h[NPR&1], h1l[NPR&1], linW, linb, out);
  (void)in_sizes; (void)n_in; (void)out_size; (void)ws_size;
}